// Round 4
// baseline (947.157 us; speedup 1.0000x reference)
//
#include <hip/hip_runtime.h>
#include <hip/hip_bf16.h>

#define VOCAB 50257
#define NPAD  50432   // 197 * 256
#define MROWS 4096    // B*S
#define SEQ   2048
#define KDIM  1024
#define NT    16      // K-tiles of BK=64

typedef __attribute__((ext_vector_type(4))) float f32x4;
typedef __attribute__((ext_vector_type(8))) short bf16x8;

#define AS1 __attribute__((address_space(1)))
#define AS3 __attribute__((address_space(3)))

__device__ __forceinline__ void bar() {
  asm volatile("" ::: "memory");
  __builtin_amdgcn_s_barrier();
  asm volatile("" ::: "memory");
}

__device__ __forceinline__ unsigned int f2bf_pair(float lo, float hi) {
  unsigned int a = __float_as_uint(lo);
  a = (a + 0x7FFFu + ((a >> 16) & 1u)) >> 16;
  unsigned int b = __float_as_uint(hi);
  b = (b + 0x7FFFu + ((b >> 16) & 1u)) >> 16;
  return a | (b << 16);
}

__global__ void cast_hidden_k(const float* __restrict__ src, uint4* __restrict__ dst) {
  int i = blockIdx.x * 256 + threadIdx.x;
  const float4* s = ((const float4*)src) + (size_t)i * 2;
  float4 a = s[0], b = s[1];
  uint4 o;
  o.x = f2bf_pair(a.x, a.y);
  o.y = f2bf_pair(a.z, a.w);
  o.z = f2bf_pair(b.x, b.y);
  o.w = f2bf_pair(b.z, b.w);
  dst[i] = o;
}

__global__ void cast_weight_k(const float* __restrict__ src, uint4* __restrict__ dst) {
  int i = blockIdx.x * 256 + threadIdx.x;
  int row = i >> 7;
  uint4 o = make_uint4(0u, 0u, 0u, 0u);
  if (row < VOCAB) {
    const float4* s = ((const float4*)src) + (size_t)i * 2;
    float4 a = s[0], b = s[1];
    o.x = f2bf_pair(a.x, a.y);
    o.y = f2bf_pair(a.z, a.w);
    o.z = f2bf_pair(b.x, b.y);
    o.w = f2bf_pair(b.z, b.w);
  }
  dst[i] = o;
}

// issue one half-tile stage (2 x global_load_lds of 16B/lane). base is per-lane
// pre-swizzled (includes lrow*KDIM + lcol). bufb/h select LDS region (elems).
#define STAGE_X(base, h, bufb, isB, kt) do { \
  const unsigned short* _g = (base) + (size_t)((h)*128 + w*8) * KDIM + (kt)*64; \
  unsigned short* _l = LDS_ + (bufb) + (isB)*16384 + (h)*8192 + w*512; \
  __builtin_amdgcn_global_load_lds((const AS1 void*)_g, (AS3 void*)_l, 16, 0, 0); \
  __builtin_amdgcn_global_load_lds((const AS1 void*)(_g + (size_t)64*KDIM), (AS3 void*)(_l + 4096), 16, 0, 0); \
} while (0)

// 256x256 tile, BK=64, 8 waves (2M x 4N), 8-phase schedule w/ counted vmcnt.
__global__ __launch_bounds__(512, 2) void gemm_ce_k(
    const unsigned short* __restrict__ A,   // [MROWS][KDIM] bf16
    const unsigned short* __restrict__ W,   // [NPAD][KDIM] bf16 (zero-padded)
    const int* __restrict__ labels,
    float* __restrict__ row_sum,            // pre-zeroed
    float* __restrict__ picked)
{
  __shared__ __align__(16) unsigned short LDS_[65536];  // 128 KiB: [2 dbuf][A 32KB | B 32KB]

  const int bid  = blockIdx.x;
  const int wg   = (bid & 7) * 394 + (bid >> 3);  // XCD chunk swizzle (3152 = 8*394)
  const int mblk = wg & 15;                       // 16 M-blocks, fastest: share W panel
  const int nblk = wg >> 4;                       // 197 vocab panels
  const int tid  = threadIdx.x;
  const int lane = tid & 63;
  const int w    = tid >> 6;                      // wave 0..7
  const int wm   = w >> 2;                        // 0..1 (128 rows each)
  const int wn   = w & 3;                         // 0..3 (64 cols each)

  const int arow0 = mblk * 256;
  const int wrow0 = nblk * 256;

  // staging geometry: lane covers row (lane>>3), pre-swizzled col within BK window
  const int lrow = lane >> 3;
  const int lcol = ((lane & 7) * 8) ^ ((lane >> 3) << 3);   // inverse of read swizzle
  const unsigned short* Abase = A + (size_t)(arow0 + lrow) * KDIM + lcol;
  const unsigned short* Wbase = W + (size_t)(wrow0 + lrow) * KDIM + lcol;

  // frag-read geometry: row (lane&15), k-chunk (lane>>4)*8; swizzle elem ^= (lane&7)<<3
  const int rbase = (lane & 15) * 64 + (lane >> 4) * 8;
  const int xorm  = (lane & 7) << 3;

  f32x4 acc[8][4];
#pragma unroll
  for (int m = 0; m < 8; ++m)
#pragma unroll
    for (int n = 0; n < 4; ++n) acc[m][n] = (f32x4){0.f, 0.f, 0.f, 0.f};

  // prologue: tile0 {A0,A1,B0,B1} -> buf0; tile1 {A0,A1} -> buf1
  STAGE_X(Abase, 0, 0, 0, 0);
  STAGE_X(Abase, 1, 0, 0, 0);
  STAGE_X(Wbase, 0, 0, 1, 0);
  STAGE_X(Wbase, 1, 0, 1, 0);
  STAGE_X(Abase, 0, 32768, 0, 1);
  STAGE_X(Abase, 1, 32768, 0, 1);
  asm volatile("s_waitcnt vmcnt(4)" ::: "memory");  // tile0 landed; tile1 A-halves in flight
  bar();

  bf16x8 Af[2][4][2], Bf[2][2][2];

  for (int t = 0; t < NT; ++t) {
    const int cb = (t & 1) << 15;          // current buffer (elems)
    const int nb = cb ^ 32768;             // next buffer

    // ---- phase 0: read A-half(wm) lo + B-quarter lo; stage B.h0(t+1) ----
#pragma unroll
    for (int a = 0; a < 4; ++a)
#pragma unroll
      for (int ks = 0; ks < 2; ++ks)
        Af[0][a][ks] = *(const bf16x8*)&LDS_[cb + (((wm*128 + a*16)*64 + rbase + ks*32) ^ xorm)];
#pragma unroll
    for (int b2 = 0; b2 < 2; ++b2)
#pragma unroll
      for (int ks = 0; ks < 2; ++ks)
        Bf[0][b2][ks] = *(const bf16x8*)&LDS_[cb + 16384 + (((wn*64 + b2*16)*64 + rbase + ks*32) ^ xorm)];
    if (t + 1 < NT) STAGE_X(Wbase, 0, nb, 1, t + 1);
    bar();
    __builtin_amdgcn_s_setprio(1);
#pragma unroll
    for (int a = 0; a < 4; ++a)
#pragma unroll
      for (int b2 = 0; b2 < 2; ++b2) {
        acc[a][b2] = __builtin_amdgcn_mfma_f32_16x16x32_bf16(Af[0][a][0], Bf[0][b2][0], acc[a][b2], 0, 0, 0);
        acc[a][b2] = __builtin_amdgcn_mfma_f32_16x16x32_bf16(Af[0][a][1], Bf[0][b2][1], acc[a][b2], 0, 0, 0);
      }
    __builtin_amdgcn_s_setprio(0);
    bar();

    // ---- phase 1: read A-half(wm) hi + B-quarter hi; stage B.h1(t+1) ----
#pragma unroll
    for (int a = 0; a < 4; ++a)
#pragma unroll
      for (int ks = 0; ks < 2; ++ks)
        Af[1][a][ks] = *(const bf16x8*)&LDS_[cb + (((wm*128 + 64 + a*16)*64 + rbase + ks*32) ^ xorm)];
#pragma unroll
    for (int b2 = 0; b2 < 2; ++b2)
#pragma unroll
      for (int ks = 0; ks < 2; ++ks)
        Bf[1][b2][ks] = *(const bf16x8*)&LDS_[cb + 16384 + (((wn*64 + 32 + b2*16)*64 + rbase + ks*32) ^ xorm)];
    if (t + 1 < NT) STAGE_X(Wbase, 1, nb, 1, t + 1);
    bar();
    __builtin_amdgcn_s_setprio(1);
#pragma unroll
    for (int a = 0; a < 4; ++a)
#pragma unroll
      for (int b2 = 0; b2 < 2; ++b2) {
        acc[a][2+b2] = __builtin_amdgcn_mfma_f32_16x16x32_bf16(Af[0][a][0], Bf[1][b2][0], acc[a][2+b2], 0, 0, 0);
        acc[a][2+b2] = __builtin_amdgcn_mfma_f32_16x16x32_bf16(Af[0][a][1], Bf[1][b2][1], acc[a][2+b2], 0, 0, 0);
      }
    __builtin_amdgcn_s_setprio(0);
    bar();  // after this barrier all reads of cb are retired chip-wide

    // ---- phase 2: stage A.h0(t+2) into cb (safe: cb reads dead) ----
    if (t + 2 < NT) STAGE_X(Abase, 0, cb, 0, t + 2);
    bar();
    __builtin_amdgcn_s_setprio(1);
#pragma unroll
    for (int a = 0; a < 4; ++a)
#pragma unroll
      for (int b2 = 0; b2 < 2; ++b2) {
        acc[4+a][b2] = __builtin_amdgcn_mfma_f32_16x16x32_bf16(Af[1][a][0], Bf[0][b2][0], acc[4+a][b2], 0, 0, 0);
        acc[4+a][b2] = __builtin_amdgcn_mfma_f32_16x16x32_bf16(Af[1][a][1], Bf[0][b2][1], acc[4+a][b2], 0, 0, 0);
      }
    __builtin_amdgcn_s_setprio(0);
    bar();

    // ---- phase 3: stage A.h1(t+2); boundary counted-vmcnt ----
    if (t + 2 < NT) STAGE_X(Abase, 1, cb, 0, t + 2);
    bar();
    __builtin_amdgcn_s_setprio(1);
#pragma unroll
    for (int a = 0; a < 4; ++a)
#pragma unroll
      for (int b2 = 0; b2 < 2; ++b2) {
        acc[4+a][2+b2] = __builtin_amdgcn_mfma_f32_16x16x32_bf16(Af[1][a][0], Bf[1][b2][0], acc[4+a][2+b2], 0, 0, 0);
        acc[4+a][2+b2] = __builtin_amdgcn_mfma_f32_16x16x32_bf16(Af[1][a][1], Bf[1][b2][1], acc[4+a][2+b2], 0, 0, 0);
      }
    __builtin_amdgcn_s_setprio(0);
    if (t < NT - 2) { asm volatile("s_waitcnt vmcnt(4)" ::: "memory"); }  // t+1 landed, t+2 A-halves in flight
    else           { asm volatile("s_waitcnt vmcnt(0)" ::: "memory"); }  // tail drain
    bar();
  }

  // epilogue: acc[m8][n4] -> row arow0+wm*128+m8*16+(lane>>4)*4+r, col wrow0+wn*64+n4*16+(lane&15)
  const int arow_w = arow0 + wm * 128;
  const int vcol_w = wrow0 + wn * 64;
#pragma unroll
  for (int m8 = 0; m8 < 8; ++m8) {
#pragma unroll
    for (int r = 0; r < 4; ++r) {
      const int grow = arow_w + m8 * 16 + (lane >> 4) * 4 + r;
      int lab = -1;
      if ((grow & (SEQ - 1)) != (SEQ - 1)) lab = labels[grow + 1];  // shifted label
      float s = 0.f;
#pragma unroll
      for (int n4 = 0; n4 < 4; ++n4) {
        const int v = vcol_w + n4 * 16 + (lane & 15);
        const float z = acc[m8][n4][r];
        const float e2 = __expf(z * (2.f / 30.f));                   // softcap via exp
        const float capped = 30.f * (1.f - 2.f * __builtin_amdgcn_rcpf(e2 + 1.f));
        if (v == lab) picked[grow] = capped;
        s += (v < VOCAB) ? __expf(capped) : 0.f;
      }
      s += __shfl_xor(s, 1);
      s += __shfl_xor(s, 2);
      s += __shfl_xor(s, 4);
      s += __shfl_xor(s, 8);
      if ((lane & 15) == 0) atomicAdd(&row_sum[grow], s);
    }
  }
}

__global__ void reduce_k(const int* __restrict__ labels, const float* __restrict__ row_sum,
                         const float* __restrict__ picked, float* __restrict__ out)
{
  const int tid = threadIdx.x;
  float ce = 0.f, zl = 0.f;
  int cnt = 0;
  for (int r = tid; r < MROWS; r += 256) {
    if ((r & (SEQ - 1)) == (SEQ - 1)) continue;
    const int lab = labels[r + 1];
    if (lab == -100) continue;
    const float lz = __logf(row_sum[r]);   // logits capped at +-30 -> no-max LSE safe
    ce += lz - picked[r];
    zl += lz * lz;
    ++cnt;
  }
  __shared__ float sce[4], szl[4];
  __shared__ int scnt[4];
#pragma unroll
  for (int off = 32; off > 0; off >>= 1) {
    ce  += __shfl_down(ce, off);
    zl  += __shfl_down(zl, off);
    cnt += __shfl_down(cnt, off);
  }
  const int wv = tid >> 6;
  if ((tid & 63) == 0) { sce[wv] = ce; szl[wv] = zl; scnt[wv] = cnt; }
  __syncthreads();
  if (tid == 0) {
    float C = 0.f, Z = 0.f;
    int N = 0;
    for (int i = 0; i < 4; ++i) { C += sce[i]; Z += szl[i]; N += scnt[i]; }
    if (N < 1) N = 1;
    out[0] = C / N + 1e-4f * (Z / N);
  }
}

extern "C" void kernel_launch(void* const* d_in, const int* in_sizes, int n_in,
                              void* d_out, int out_size, void* d_ws, size_t ws_size,
                              hipStream_t stream) {
  const float* hidden = (const float*)d_in[0];
  const float* weight = (const float*)d_in[1];
  const int*   labels = (const int*)d_in[2];
  float* out = (float*)d_out;

  const size_t A_BYTES = (size_t)MROWS * KDIM * 2;
  const size_t W_BYTES = (size_t)NPAD * KDIM * 2;
  const size_t NEEDED  = A_BYTES + W_BYTES + 2 * MROWS * sizeof(float);
  if (ws_size < NEEDED) return;  // loud failure instead of OOB crash

  char* ws = (char*)d_ws;
  unsigned short* Abf = (unsigned short*)ws;
  unsigned short* Wbf = (unsigned short*)(ws + A_BYTES);
  float* row_sum = (float*)(ws + A_BYTES + W_BYTES);
  float* picked  = row_sum + MROWS;

  hipMemsetAsync(row_sum, 0, MROWS * sizeof(float), stream);
  cast_hidden_k<<<MROWS * KDIM / 8 / 256, 256, 0, stream>>>(hidden, (uint4*)Abf);
  cast_weight_k<<<NPAD * KDIM / 8 / 256, 256, 0, stream>>>(weight, (uint4*)Wbf);
  gemm_ce_k<<<16 * 197 /* =3152 */, 512, 0, stream>>>(Abf, Wbf, labels, row_sum, picked);
  reduce_k<<<1, 256, 0, stream>>>(labels, row_sum, picked, out);
}

// Round 5
// 812.645 us; speedup vs baseline: 1.1655x; 1.1655x over previous
//
#include <hip/hip_runtime.h>
#include <hip/hip_bf16.h>

#define VOCAB 50257
#define NPAD  50432   // 197 * 256
#define NBLKS 197
#define MROWS 4096    // B*S
#define SEQ   2048
#define KDIM  1024
#define NT    16      // K-tiles of BK=64

typedef __attribute__((ext_vector_type(4))) float f32x4;
typedef __attribute__((ext_vector_type(8))) short bf16x8;

#define AS1 __attribute__((address_space(1)))
#define AS3 __attribute__((address_space(3)))

__device__ __forceinline__ void bar() {
  asm volatile("" ::: "memory");
  __builtin_amdgcn_s_barrier();
  asm volatile("" ::: "memory");
}

__device__ __forceinline__ unsigned int f2bf_pair(float lo, float hi) {
  unsigned int a = __float_as_uint(lo);
  a = (a + 0x7FFFu + ((a >> 16) & 1u)) >> 16;
  unsigned int b = __float_as_uint(hi);
  b = (b + 0x7FFFu + ((b >> 16) & 1u)) >> 16;
  return a | (b << 16);
}

__global__ void cast_hidden_k(const float* __restrict__ src, uint4* __restrict__ dst) {
  int i = blockIdx.x * 256 + threadIdx.x;
  const float4* s = ((const float4*)src) + (size_t)i * 2;
  float4 a = s[0], b = s[1];
  uint4 o;
  o.x = f2bf_pair(a.x, a.y);
  o.y = f2bf_pair(a.z, a.w);
  o.z = f2bf_pair(b.x, b.y);
  o.w = f2bf_pair(b.z, b.w);
  dst[i] = o;
}

__global__ void cast_weight_k(const float* __restrict__ src, uint4* __restrict__ dst) {
  int i = blockIdx.x * 256 + threadIdx.x;
  int row = i >> 7;
  uint4 o = make_uint4(0u, 0u, 0u, 0u);
  if (row < VOCAB) {
    const float4* s = ((const float4*)src) + (size_t)i * 2;
    float4 a = s[0], b = s[1];
    o.x = f2bf_pair(a.x, a.y);
    o.y = f2bf_pair(a.z, a.w);
    o.z = f2bf_pair(b.x, b.y);
    o.w = f2bf_pair(b.z, b.w);
  }
  dst[i] = o;
}

// one half-tile stage: 2 x global_load_lds(16B/lane). base pre-swizzled per lane.
#define STAGE_X(base, h, bufb, isB, kt) do { \
  const unsigned short* _g = (base) + (size_t)((h)*128 + w*8) * KDIM + (kt)*64; \
  unsigned short* _l = LDS_ + (bufb) + (isB)*16384 + (h)*8192 + w*512; \
  __builtin_amdgcn_global_load_lds((const AS1 void*)_g, (AS3 void*)_l, 16, 0, 0); \
  __builtin_amdgcn_global_load_lds((const AS1 void*)(_g + (size_t)64*KDIM), (AS3 void*)(_l + 4096), 16, 0, 0); \
} while (0)

// 256x256 tile, BK=64, 8 waves (2M x 4N), 4 phases/K-tile, counted vmcnt.
__global__ __launch_bounds__(512) void gemm_ce_k(
    const unsigned short* __restrict__ A,   // [MROWS][KDIM] bf16
    const unsigned short* __restrict__ W,   // [NPAD][KDIM] bf16 (zero-padded)
    const int* __restrict__ labels,
    float* __restrict__ partial,            // [NBLKS][MROWS]
    float* __restrict__ picked)
{
  __shared__ __align__(16) unsigned short LDS_[65536];  // 128 KiB: [2 dbuf][A 32KB | B 32KB]

  const int bid  = blockIdx.x;
  const int wg   = (bid & 7) * 394 + (bid >> 3);  // XCD chunk swizzle (3152 = 8*394)
  const int mblk = wg & 15;
  const int nblk = wg >> 4;
  const int tid  = threadIdx.x;
  const int lane = tid & 63;
  const int w    = tid >> 6;
  const int wm   = w >> 2;                        // 0..1 (128 rows)
  const int wn   = w & 3;                         // 0..3 (64 cols)

  const int arow0 = mblk * 256;
  const int wrow0 = nblk * 256;

  const int lrow = lane >> 3;
  const int lcol = ((lane & 7) * 8) ^ ((lane >> 3) << 3);   // inverse of read swizzle
  const unsigned short* Abase = A + (size_t)(arow0 + lrow) * KDIM + lcol;
  const unsigned short* Wbase = W + (size_t)(wrow0 + lrow) * KDIM + lcol;

  const int rbase = (lane & 15) * 64 + (lane >> 4) * 8;
  const int xorm  = (lane & 7) << 3;

  f32x4 acc[8][4];
#pragma unroll
  for (int m = 0; m < 8; ++m)
#pragma unroll
    for (int n = 0; n < 4; ++n) acc[m][n] = (f32x4){0.f, 0.f, 0.f, 0.f};

  // prologue: tile0 full -> buf0; tile1 A -> buf1
  STAGE_X(Abase, 0, 0, 0, 0);
  STAGE_X(Abase, 1, 0, 0, 0);
  STAGE_X(Wbase, 0, 0, 1, 0);
  STAGE_X(Wbase, 1, 0, 1, 0);
  STAGE_X(Abase, 0, 32768, 0, 1);
  STAGE_X(Abase, 1, 32768, 0, 1);
  asm volatile("s_waitcnt vmcnt(4)" ::: "memory");
  bar();

  bf16x8 Af[4][2], Bf[2][2][2];

#pragma unroll 1
  for (int t = 0; t < NT; ++t) {
    const int cb = (t & 1) << 15;
    const int nb = cb ^ 32768;

    // ---- ph0: read Af(lo)+Bf0; stage B.h0(t+1)->nb; MFMA q00 ----
#pragma unroll
    for (int a = 0; a < 4; ++a)
#pragma unroll
      for (int ks = 0; ks < 2; ++ks)
        Af[a][ks] = *(const bf16x8*)&LDS_[cb + (((wm*128 + a*16)*64 + rbase + ks*32) ^ xorm)];
#pragma unroll
    for (int b2 = 0; b2 < 2; ++b2)
#pragma unroll
      for (int ks = 0; ks < 2; ++ks)
        Bf[0][b2][ks] = *(const bf16x8*)&LDS_[cb + 16384 + (((wn*64 + b2*16)*64 + rbase + ks*32) ^ xorm)];
    if (t + 1 < NT) STAGE_X(Wbase, 0, nb, 1, t + 1);
    bar();
    __builtin_amdgcn_s_setprio(1);
#pragma unroll
    for (int a = 0; a < 4; ++a)
#pragma unroll
      for (int b2 = 0; b2 < 2; ++b2) {
        acc[a][b2] = __builtin_amdgcn_mfma_f32_16x16x32_bf16(Af[a][0], Bf[0][b2][0], acc[a][b2], 0, 0, 0);
        acc[a][b2] = __builtin_amdgcn_mfma_f32_16x16x32_bf16(Af[a][1], Bf[0][b2][1], acc[a][b2], 0, 0, 0);
      }
    __builtin_amdgcn_s_setprio(0);
    bar();

    // ---- ph1: read Bf1; stage B.h1(t+1)->nb; MFMA q01 = Af(lo) x Bf1 ----
#pragma unroll
    for (int b2 = 0; b2 < 2; ++b2)
#pragma unroll
      for (int ks = 0; ks < 2; ++ks)
        Bf[1][b2][ks] = *(const bf16x8*)&LDS_[cb + 16384 + (((wn*64 + 32 + b2*16)*64 + rbase + ks*32) ^ xorm)];
    if (t + 1 < NT) STAGE_X(Wbase, 1, nb, 1, t + 1);
    bar();
    __builtin_amdgcn_s_setprio(1);
#pragma unroll
    for (int a = 0; a < 4; ++a)
#pragma unroll
      for (int b2 = 0; b2 < 2; ++b2) {
        acc[a][2+b2] = __builtin_amdgcn_mfma_f32_16x16x32_bf16(Af[a][0], Bf[1][b2][0], acc[a][2+b2], 0, 0, 0);
        acc[a][2+b2] = __builtin_amdgcn_mfma_f32_16x16x32_bf16(Af[a][1], Bf[1][b2][1], acc[a][2+b2], 0, 0, 0);
      }
    __builtin_amdgcn_s_setprio(0);
    bar();

    // ---- ph2: read Af(hi) overwrite; drain lgkm; stage A.h0(t+2)->cb; MFMA q10 ----
#pragma unroll
    for (int a = 0; a < 4; ++a)
#pragma unroll
      for (int ks = 0; ks < 2; ++ks)
        Af[a][ks] = *(const bf16x8*)&LDS_[cb + (((wm*128 + 64 + a*16)*64 + rbase + ks*32) ^ xorm)];
    asm volatile("s_waitcnt lgkmcnt(0)" ::: "memory");   // reads retired before A-region overwrite
    __builtin_amdgcn_sched_barrier(0);
    if (t + 2 < NT) STAGE_X(Abase, 0, cb, 0, t + 2);
    bar();
    __builtin_amdgcn_s_setprio(1);
#pragma unroll
    for (int a = 0; a < 4; ++a)
#pragma unroll
      for (int b2 = 0; b2 < 2; ++b2) {
        acc[4+a][b2] = __builtin_amdgcn_mfma_f32_16x16x32_bf16(Af[a][0], Bf[0][b2][0], acc[4+a][b2], 0, 0, 0);
        acc[4+a][b2] = __builtin_amdgcn_mfma_f32_16x16x32_bf16(Af[a][1], Bf[0][b2][1], acc[4+a][b2], 0, 0, 0);
      }
    __builtin_amdgcn_s_setprio(0);
    bar();

    // ---- ph3: no reads; stage A.h1(t+2)->cb; MFMA q11; boundary vmcnt ----
    if (t + 2 < NT) STAGE_X(Abase, 1, cb, 0, t + 2);
    bar();
    __builtin_amdgcn_s_setprio(1);
#pragma unroll
    for (int a = 0; a < 4; ++a)
#pragma unroll
      for (int b2 = 0; b2 < 2; ++b2) {
        acc[4+a][2+b2] = __builtin_amdgcn_mfma_f32_16x16x32_bf16(Af[a][0], Bf[1][b2][0], acc[4+a][2+b2], 0, 0, 0);
        acc[4+a][2+b2] = __builtin_amdgcn_mfma_f32_16x16x32_bf16(Af[a][1], Bf[1][b2][1], acc[4+a][2+b2], 0, 0, 0);
      }
    __builtin_amdgcn_s_setprio(0);
    if (t < NT - 2) { asm volatile("s_waitcnt vmcnt(4)" ::: "memory"); }
    else           { asm volatile("s_waitcnt vmcnt(0)" ::: "memory"); }
    bar();
  }

  // ---- epilogue: softcap -> exp-sum per row; LDS reduce across wn; one store/row ----
  float* red = (float*)LDS_;   // [4 wn][256 rows]
  const int arow_w = arow0 + wm * 128;
  const int vcol_w = wrow0 + wn * 64;
#pragma unroll
  for (int m8 = 0; m8 < 8; ++m8) {
#pragma unroll
    for (int r = 0; r < 4; ++r) {
      const int grow = arow_w + m8 * 16 + (lane >> 4) * 4 + r;
      int lab = -1;
      if ((grow & (SEQ - 1)) != (SEQ - 1)) lab = labels[grow + 1];
      float s = 0.f;
#pragma unroll
      for (int n4 = 0; n4 < 4; ++n4) {
        const int v = vcol_w + n4 * 16 + (lane & 15);
        const float z = acc[m8][n4][r];
        const float e2 = __expf(z * (2.f / 30.f));
        const float capped = 30.f * (1.f - 2.f * __builtin_amdgcn_rcpf(e2 + 1.f));
        if (v == lab) picked[grow] = capped;
        s += (v < VOCAB) ? __expf(capped) : 0.f;
      }
      s += __shfl_xor(s, 1);
      s += __shfl_xor(s, 2);
      s += __shfl_xor(s, 4);
      s += __shfl_xor(s, 8);
      if ((lane & 15) == 0) red[wn * 256 + (wm * 128 + m8 * 16 + (lane >> 4) * 4 + r)] = s;
    }
  }
  bar();
  if (tid < 256) {
    float s = red[tid] + red[256 + tid] + red[512 + tid] + red[768 + tid];
    partial[(size_t)nblk * MROWS + arow0 + tid] = s;
  }
}

__global__ void reduce2_k(const int* __restrict__ labels, const float* __restrict__ partial,
                          const float* __restrict__ picked, float* __restrict__ scal)
{
  const int tid = threadIdx.x;
  const int row = blockIdx.x * 256 + tid;
  float ce = 0.f, zl = 0.f, cnt = 0.f;
  int lab = -100;
  if ((row & (SEQ - 1)) != (SEQ - 1)) lab = labels[row + 1];
  if (lab != -100) {
    float s = 0.f;
    for (int p = 0; p < NBLKS; ++p) s += partial[(size_t)p * MROWS + row];  // coalesced across threads
    const float lz = __logf(s);            // |logits| <= 30 -> no-max LSE safe
    ce = lz - picked[row];
    zl = lz * lz;
    cnt = 1.f;
  }
  __shared__ float sm[3][4];
#pragma unroll
  for (int off = 32; off > 0; off >>= 1) {
    ce  += __shfl_down(ce, off);
    zl  += __shfl_down(zl, off);
    cnt += __shfl_down(cnt, off);
  }
  const int wv = tid >> 6;
  if ((tid & 63) == 0) { sm[0][wv] = ce; sm[1][wv] = zl; sm[2][wv] = cnt; }
  __syncthreads();
  if (tid == 0) {
    atomicAdd(&scal[0], sm[0][0] + sm[0][1] + sm[0][2] + sm[0][3]);
    atomicAdd(&scal[1], sm[1][0] + sm[1][1] + sm[1][2] + sm[1][3]);
    atomicAdd(&scal[2], sm[2][0] + sm[2][1] + sm[2][2] + sm[2][3]);
  }
}

__global__ void final_k(const float* __restrict__ scal, float* __restrict__ out) {
  const float n = fmaxf(scal[2], 1.f);
  out[0] = scal[0] / n + 1e-4f * (scal[1] / n);
}

extern "C" void kernel_launch(void* const* d_in, const int* in_sizes, int n_in,
                              void* d_out, int out_size, void* d_ws, size_t ws_size,
                              hipStream_t stream) {
  const float* hidden = (const float*)d_in[0];
  const float* weight = (const float*)d_in[1];
  const int*   labels = (const int*)d_in[2];
  float* out = (float*)d_out;

  const size_t A_BYTES = (size_t)MROWS * KDIM * 2;
  const size_t W_BYTES = (size_t)NPAD * KDIM * 2;
  const size_t P_BYTES = (size_t)NBLKS * MROWS * sizeof(float);   // 3.2 MB
  const size_t NEEDED  = A_BYTES + W_BYTES + P_BYTES + (MROWS + 4) * sizeof(float);
  if (ws_size < NEEDED) return;  // loud failure instead of OOB crash

  char* ws = (char*)d_ws;
  unsigned short* Abf = (unsigned short*)ws;
  unsigned short* Wbf = (unsigned short*)(ws + A_BYTES);
  float* partial = (float*)(ws + A_BYTES + W_BYTES);
  float* picked  = partial + (size_t)NBLKS * MROWS;
  float* scal    = picked + MROWS;

  hipMemsetAsync(scal, 0, 3 * sizeof(float), stream);
  cast_hidden_k<<<MROWS * KDIM / 8 / 256, 256, 0, stream>>>(hidden, (uint4*)Abf);
  cast_weight_k<<<NPAD * KDIM / 8 / 256, 256, 0, stream>>>(weight, (uint4*)Wbf);
  gemm_ce_k<<<16 * NBLKS /* 3152 */, 512, 0, stream>>>(Abf, Wbf, labels, partial, picked);
  reduce2_k<<<MROWS / 256, 256, 0, stream>>>(labels, partial, picked, scal);
  final_k<<<1, 1, 0, stream>>>(scal, out);
}